// Round 14
// baseline (316.591 us; speedup 1.0000x reference)
//
#include <hip/hip_runtime.h>
#include <hip/hip_bf16.h>
#include <math.h>

#define B_   8
#define C_   256
#define CI_  128
#define N_   4096

typedef unsigned short ushort_t;
typedef unsigned int uint_t;
typedef __attribute__((ext_vector_type(8))) short short8;
typedef __attribute__((ext_vector_type(16))) float floatx16;
typedef __attribute__((ext_vector_type(2))) unsigned int uint2v;

// workspace layout (byte offsets)
#define OFF_W3B  0ull           // bf16 [384][256]
#define OFF_B3   196608ull      // fp32 [384]
#define OFF_WCB  198144ull      // bf16 [256][128]
#define OFF_XT   263680ull      // bf16 [B][N][256]      16.8 MB
#define OFF_THT  17040896ull    // bf16 [B][N][128]      8.4 MB
#define OFF_PHT  25429504ull    // bf16 [B][N][128]      8.4 MB
#define OFF_G16  33818112ull    // bf16 [B][128][N]      8.4 MB
#define OFF_LP   42206720ull    // fp32 [2][B][N]        256 KB
#define OFF_YPB  42468864ull    // bf16 [2][B][N][128]   16.8 MB
#define OFF_WY   263680ull      // bf16 [B][256][N] — overlays XT (dead by wgemm)
#define OFF_ST   59246080ull    // fp32 [2][256] raw sums (zeroed by pack path)

__device__ __forceinline__ ushort_t f2bf(float x) {
  union { float f; uint_t u; } c; c.f = x;
  return (ushort_t)((c.u + 0x7fffu + ((c.u >> 16) & 1u)) >> 16);
}
__device__ __forceinline__ uint_t pkbf(float a, float b) {
  __hip_bfloat162 h = __float22bfloat162_rn(float2{a, b});
  union { __hip_bfloat162 h; uint_t u; } c; c.h = h; return c.u;
}
__device__ __forceinline__ float bf_lo(uint_t u) {
  union { uint_t u; float f; } c; c.u = u << 16; return c.f;
}
__device__ __forceinline__ float bf_hi(uint_t u) {
  union { uint_t u; float f; } c; c.u = u & 0xffff0000u; return c.f;
}
// raw hw exp2 (skip OCML denormal-guard path); s_nop covers trans->valu hazard
__device__ __forceinline__ float fexp2(float x) {
  float r; asm("v_exp_f32 %0, %1\ns_nop 0" : "=v"(r) : "v"(x)); return r;
}
__device__ __forceinline__ void async_copy16(const void* g, void* l) {
  __builtin_amdgcn_global_load_lds(
      (const __attribute__((address_space(1))) unsigned int*)g,
      (__attribute__((address_space(3))) unsigned int*)l, 16, 0, 0);
}

// -------- fused: pack weights + zero BN sums + x transpose/cast -------------
// bid < 384: W3b pack; < 512: Wc pack; == 512: zero st; >= 513: xcast tile
__global__ __launch_bounds__(256) void pack_xcast(
    const float* __restrict__ g_w, const float* __restrict__ g_b,
    const float* __restrict__ th_w, const float* __restrict__ th_b,
    const float* __restrict__ ph_w, const float* __restrict__ ph_b,
    const float* __restrict__ W_w, const float* __restrict__ x,
    ushort_t* __restrict__ W3b, float* __restrict__ b3,
    ushort_t* __restrict__ Wc, float* __restrict__ st,
    ushort_t* __restrict__ xt)
{
  const int bid = blockIdx.x;
  const int tid = threadIdx.x;
  __shared__ float xs[64][65];
  if (bid < 384) {
    int i = bid * 256 + tid;
    int o = i >> 8;
    float v;
    if (o < 128)      v = g_w[i];
    else if (o < 256) v = th_w[i - 128*256];
    else              v = ph_w[i - 256*256];
    W3b[i] = f2bf(v);
    if ((i & 255) == 0)
      b3[o] = (o < 128) ? g_b[o] : (o < 256) ? th_b[o - 128] : ph_b[o - 256];
    return;
  } else if (bid < 512) {
    int j = (bid - 384) * 256 + tid;   // < 32768
    Wc[j] = f2bf(W_w[j]);
    return;
  } else if (bid == 512) {
    st[tid] = 0.f;
    st[256 + tid] = 0.f;
    return;
  }
  // xcast: idx -> (b, c-tile, n-tile); 8 x 4 x 64 = 2048 tiles
  const int idx = bid - 513;
  const int b = idx >> 8, cb = (idx >> 6) & 3, nb = idx & 63;
  const int c0 = cb * 64, n0 = nb * 64;
  const int nq = (tid & 15) * 4, cr = tid >> 4;
  #pragma unroll
  for (int i = 0; i < 4; ++i) {
    float4 v = *(const float4*)&x[((size_t)b * C_ + c0 + cr + 16*i) * N_ + n0 + nq];
    xs[cr + 16*i][nq] = v.x; xs[cr + 16*i][nq+1] = v.y;
    xs[cr + 16*i][nq+2] = v.z; xs[cr + 16*i][nq+3] = v.w;
  }
  __syncthreads();
  const int n = tid >> 2, cs = (tid & 3) * 16;
  uint_t u[8];
  #pragma unroll
  for (int j = 0; j < 8; ++j)
    u[j] = pkbf(xs[cs + 2*j][n], xs[cs + 2*j + 1][n]);
  ushort_t* dst = &xt[((size_t)b * N_ + n0 + n) * C_ + c0 + cs];
  *(uint4*)dst       = make_uint4(u[0], u[1], u[2], u[3]);
  *(uint4*)(dst + 8) = make_uint4(u[4], u[5], u[6], u[7]);
}

// -------- projection GEMM v2: double-buffered issue-early staging -----------
__global__ __launch_bounds__(256, 2) void proj_all(
    const ushort_t* __restrict__ W3b, const float* __restrict__ b3,
    const ushort_t* __restrict__ xt, ushort_t* __restrict__ tht,
    ushort_t* __restrict__ pht, ushort_t* __restrict__ g16)
{
  const int b = blockIdx.z, nb = blockIdx.x, ot = blockIdx.y;
  const int gm = (ot == 2);
  const int o0 = gm ? 0 : (128 + ot * 128);
  const int tid = threadIdx.x, w = tid >> 6, lane = tid & 63;
  const int l31 = lane & 31, h = lane >> 5, xk = l31 & 7;
  __shared__ ushort_t ws_l[2 * 128 * 64];   // 32 KB
  __shared__ ushort_t xs_l[2 * 128 * 64];   // 32 KB
  const ushort_t* xb = xt + (size_t)b * N_ * C_;
  const int n0 = nb * 128;
  floatx16 acc[4];
  #pragma unroll
  for (int ct = 0; ct < 4; ++ct)
    #pragma unroll
    for (int r = 0; r < 16; ++r) acc[ct][r] = 0.f;

  const int gr = lane >> 3, gu = lane & 7;

  #define PSTAGE(k0v, bufv)                                                   \
    {                                                                         \
      ushort_t* wsb = ws_l + (bufv) * 8192;                                   \
      ushort_t* xsb = xs_l + (bufv) * 8192;                                   \
      _Pragma("unroll")                                                       \
      for (int i = 0; i < 4; ++i) {                                           \
        int r = w*32 + i*8 + gr;                                              \
        async_copy16(&W3b[(size_t)(o0 + r) * C_ + (k0v) + ((gu ^ (r & 7)) * 8)], \
                     &wsb[(w*32 + i*8) * 64]);                                \
        async_copy16(&xb[(size_t)(n0 + r) * C_ + (k0v) + ((gu ^ (r & 7)) * 8)],  \
                     &xsb[(w*32 + i*8) * 64]);                                \
      }                                                                       \
    }

  PSTAGE(0, 0);
  asm volatile("s_waitcnt vmcnt(0)" ::: "memory");
  __builtin_amdgcn_s_barrier();

  for (int kt = 0; kt < 4; ++kt) {
    const int cur = kt & 1;
    if (kt < 3) PSTAGE((kt + 1) * 64, cur ^ 1);
    const ushort_t* wsb = ws_l + cur * 8192;
    const ushort_t* xsb = xs_l + cur * 8192;
    const ushort_t* bmat = gm ? wsb : xsb;
    const ushort_t* amat = gm ? xsb : wsb;
    #pragma unroll
    for (int kk = 0; kk < 4; ++kk) {
      int fc = ((2*kk + h) ^ xk) * 8;
      short8 bf = *(const short8*)&bmat[(w*32 + l31) * 64 + fc];
      #pragma unroll
      for (int ct = 0; ct < 4; ++ct) {
        short8 af = *(const short8*)&amat[(ct*32 + l31) * 64 + fc];
        acc[ct] = __builtin_amdgcn_mfma_f32_32x32x16_bf16(af, bf, acc[ct], 0, 0, 0);
      }
    }
    asm volatile("s_waitcnt vmcnt(0)" ::: "memory");
    __builtin_amdgcn_s_barrier();
  }

  if (gm) {
    float bv = b3[w*32 + l31];
    ushort_t* gp = g16 + ((size_t)b * CI_ + w*32 + l31) * N_;
    #pragma unroll
    for (int ct = 0; ct < 4; ++ct)
      #pragma unroll
      for (int rq = 0; rq < 4; ++rq) {
        uint2 d = make_uint2(pkbf(acc[ct][4*rq+0] + bv, acc[ct][4*rq+1] + bv),
                             pkbf(acc[ct][4*rq+2] + bv, acc[ct][4*rq+3] + bv));
        *(uint2*)&gp[n0 + ct*32 + 8*rq + 4*h] = d;
      }
  } else {
    ushort_t* tp = ((ot == 0) ? tht : pht) + ((size_t)b * N_ + n0 + w*32 + l31) * CI_;
    #pragma unroll
    for (int ct = 0; ct < 4; ++ct)
      #pragma unroll
      for (int rq = 0; rq < 4; ++rq) {
        float4 bv = *(const float4*)&b3[o0 + ct*32 + 8*rq + 4*h];
        uint2 d = make_uint2(pkbf(acc[ct][4*rq+0] + bv.x, acc[ct][4*rq+1] + bv.y),
                             pkbf(acc[ct][4*rq+2] + bv.z, acc[ct][4*rq+3] + bv.w));
        *(uint2*)&tp[ct*32 + 8*rq + 4*h] = d;
      }
  }
}

// ---------------------------------------------------------------------------
// MFMA flash attention v6: round-10 schedule with QK1 hoisted before SMPV0 —
// QK1's dependent MFMA chain (results needed only in SMPV1) drains under
// SMPV0's softmax VALU. +16 VGPR (s1 live across SMPV0): 148 -> ~164 of the
// 168 cap. Spill tripwire: WRITE_SIZE >> 23.3 MB.
// ---------------------------------------------------------------------------
#define LOG2E_  1.442695041f
#define MBIAS_  (-28.85390082f)   /* = -20 * log2(e) */

__global__ __launch_bounds__(256, 3) void attn_mfma(
    const ushort_t* __restrict__ tht, const ushort_t* __restrict__ pht,
    const ushort_t* __restrict__ g16, ushort_t* __restrict__ yp,
    float* __restrict__ lp)
{
  const int b  = blockIdx.x & 7;           // batch -> XCD
  const int ms = (blockIdx.x >> 3) & 1;    // key split
  const int qb = blockIdx.x >> 4;          // 0..31
  const int tid = threadIdx.x, w = tid >> 6, lane = tid & 63;
  const int l31 = lane & 31, h = lane >> 5, xk = l31 & 7;

  // smem (ushort idx): phs[2] @0 (each 64x128=8192), gs @16384 (128x64=8192)
  __shared__ ushort_t smem[24576];   // 48 KB -> 3 blocks/CU

  const int q0w = qb * 128 + w * 32;
  const int m_base = ms * 2048;

  const ushort_t* thb = tht + (size_t)b * N_ * CI_;
  const ushort_t* phb = pht + (size_t)b * N_ * CI_;
  const ushort_t* gbp = g16 + (size_t)b * CI_ * N_;

  short8 tf[8];
  #pragma unroll
  for (int kk = 0; kk < 8; ++kk)
    tf[kk] = *(const short8*)&thb[(size_t)(q0w + l31) * CI_ + kk*16 + h*8];

  floatx16 acc[4];
  #pragma unroll
  for (int ct = 0; ct < 4; ++ct)
    #pragma unroll
    for (int r = 0; r < 16; ++r) acc[ct][r] = 0.f;
  float lpart = 0.f;

  const int phr = lane >> 4, phu = lane & 15;
  const int gr  = lane >> 3, gu  = lane & 7;

  #define STAGE_PHS(m0v, bufv)                                                \
    {                                                                         \
      ushort_t* phs_ = smem + (bufv) * 8192;                                  \
      _Pragma("unroll")                                                       \
      for (int i = 0; i < 4; ++i) {                                           \
        int row = w*16 + i*4 + phr;                                           \
        async_copy16(&phb[(size_t)((m0v) + row) * CI_ + ((phu ^ (row & 7)) * 8)], \
                     &phs_[(w*16 + i*4) * 128]);                              \
      }                                                                       \
    }
  #define STAGE_GS(m0v)                                                       \
    {                                                                         \
      ushort_t* gs_ = smem + 16384;                                           \
      _Pragma("unroll")                                                       \
      for (int i = 0; i < 4; ++i) {                                           \
        int c = w*32 + i*8 + gr;                                              \
        async_copy16(&gbp[(size_t)c * N_ + (m0v) + ((gu ^ (c & 7)) * 8)],     \
                     &gs_[(w*32 + i*8) * 64]);                                \
      }                                                                       \
    }

  #define SMPV(sv, mtv)                                                       \
    {                                                                         \
      uint_t Aw[4], Bw[4];                                                    \
      float ls = 0.f;                                                         \
      _Pragma("unroll")                                                       \
      for (int rq = 0; rq < 4; ++rq) {                                        \
        float p0 = fexp2(fmaf(sv[4*rq+0], LOG2E_, MBIAS_));                   \
        float p1 = fexp2(fmaf(sv[4*rq+1], LOG2E_, MBIAS_));                   \
        float p2 = fexp2(fmaf(sv[4*rq+2], LOG2E_, MBIAS_));                   \
        float p3 = fexp2(fmaf(sv[4*rq+3], LOG2E_, MBIAS_));                   \
        ls += (p0 + p1) + (p2 + p3);                                          \
        Aw[rq] = pkbf(p0, p1);                                                \
        Bw[rq] = pkbf(p2, p3);                                                \
      }                                                                       \
      lpart += ls;                                                            \
      _Pragma("unroll")                                                       \
      for (int t = 0; t < 2; ++t) {                                           \
        uint2v ra = __builtin_amdgcn_permlane32_swap(Aw[2*t], Aw[2*t+1], false, false); \
        uint2v rb = __builtin_amdgcn_permlane32_swap(Bw[2*t], Bw[2*t+1], false, false); \
        union { uint_t u[4]; short8 s; } pk_;                                 \
        pk_.u[0] = ra.x; pk_.u[1] = rb.x; pk_.u[2] = ra.y; pk_.u[3] = rb.y;   \
        const int pc = ((2*(2*(mtv) + t) + h) ^ xk) * 8;                      \
        __builtin_amdgcn_s_setprio(1);                                        \
        _Pragma("unroll")                                                     \
        for (int ct = 0; ct < 4; ++ct) {                                      \
          short8 gf = *(const short8*)&gs[(ct*32 + l31) * 64 + pc];           \
          acc[ct] = __builtin_amdgcn_mfma_f32_32x32x16_bf16(gf, pk_.s, acc[ct], 0, 0, 0); \
        }                                                                     \
        __builtin_amdgcn_s_setprio(0);                                        \
      }                                                                       \
    }

  const ushort_t* gs = smem + 16384;

  STAGE_PHS(m_base, 0);
  asm volatile("s_waitcnt vmcnt(0)" ::: "memory");
  __builtin_amdgcn_s_barrier();

  for (int it = 0; it < 32; ++it) {
    const int cur = it & 1;
    const int m0 = m_base + it * 64;
    STAGE_GS(m0);
    if (it < 31) STAGE_PHS(m0 + 64, cur ^ 1);
    const ushort_t* phs = smem + cur * 8192;

    // QK^T half 0 (keys m0..m0+31)
    floatx16 s0, s1;
    #pragma unroll
    for (int r = 0; r < 16; ++r) { s0[r] = 0.f; s1[r] = 0.f; }
    __builtin_amdgcn_s_setprio(1);
    #pragma unroll
    for (int kk = 0; kk < 8; ++kk) {
      short8 pf = *(const short8*)&phs[l31 * 128 + (((2*kk + h) ^ xk) * 8)];
      s0 = __builtin_amdgcn_mfma_f32_32x32x16_bf16(pf, tf[kk], s0, 0, 0, 0);
    }
    __builtin_amdgcn_s_setprio(0);

    // own gs copies done (4 newest outstanding = phs(t+1)); barrier -> all
    // waves' gs(t) visible
    if (it < 31) { asm volatile("s_waitcnt vmcnt(4)" ::: "memory"); }
    else         { asm volatile("s_waitcnt vmcnt(0)" ::: "memory"); }
    __builtin_amdgcn_s_barrier();

    // QK^T half 1 issued BEFORE SMPV0: its dependent MFMA chain (s1 not
    // read until SMPV1) drains under SMPV0's softmax VALU
    __builtin_amdgcn_s_setprio(1);
    #pragma unroll
    for (int kk = 0; kk < 8; ++kk) {
      short8 pf = *(const short8*)&phs[(32 + l31) * 128 + (((2*kk + h) ^ xk) * 8)];
      s1 = __builtin_amdgcn_mfma_f32_32x32x16_bf16(pf, tf[kk], s1, 0, 0, 0);
    }
    __builtin_amdgcn_s_setprio(0);

    SMPV(s0, 0)
    SMPV(s1, 1)

    // phs(t+1) (issued a full iter ago) drained; barrier separates this
    // iter's phs/gs reads from next iter's DMA writes
    asm volatile("s_waitcnt vmcnt(0)" ::: "memory");
    __builtin_amdgcn_s_barrier();
  }

  float lq = lpart + __shfl_xor(lpart, 32);
  if (h == 0)
    lp[((size_t)ms * 8 + b) * N_ + q0w + l31] = lq;

  __syncthreads();
  ushort_t* tr = smem + w * 4096;
  #pragma unroll
  for (int ct = 0; ct < 4; ++ct)
    #pragma unroll
    for (int rq = 0; rq < 4; ++rq) {
      uint2 d = make_uint2(pkbf(acc[ct][4*rq+0], acc[ct][4*rq+1]),
                           pkbf(acc[ct][4*rq+2], acc[ct][4*rq+3]));
      *(uint2*)&tr[l31 * 128 + ct*32 + 8*rq + 4*h] = d;
    }
  ushort_t* ypb = yp + (((size_t)ms * 8 + b) * N_ + q0w) * CI_;
  #pragma unroll
  for (int itx = 0; itx < 8; ++itx) {
    int row = itx*4 + (lane >> 4);
    int cu  = (lane & 15) * 8;
    uint4 v = *(const uint4*)&tr[row * 128 + cu];
    *(uint4*)&ypb[(size_t)row * CI_ + cu] = v;
  }
}

// -------- W-conv GEMM v2 (round-10 proven): single-shot K=128, no BN fusion -
__global__ __launch_bounds__(256, 2) void wgemm_fused(
    const ushort_t* __restrict__ Wc, const float* __restrict__ Wb,
    const ushort_t* __restrict__ yp, const float* __restrict__ lp,
    ushort_t* __restrict__ WYb)
{
  const int b = blockIdx.z, nb = blockIdx.x, ot = blockIdx.y;
  const int o0 = ot * 128;
  const int tid = threadIdx.x, w = tid >> 6, lane = tid & 63;
  const int l31 = lane & 31, h = lane >> 5, xk = l31 & 7;
  __shared__ ushort_t ws_l[128 * 128];   // 32 KB: Wc [o_local][c]
  __shared__ ushort_t xs_l[128 * 128];   // 32 KB: y  [n_local][c]
  const int n0 = nb * 128;
  const size_t PH = (size_t)B_ * N_ * CI_;
  const ushort_t* yp0 = yp + (size_t)b * N_ * CI_;
  const ushort_t* yp1 = yp0 + PH;
  floatx16 acc[4];
  #pragma unroll
  for (int ct = 0; ct < 4; ++ct)
    #pragma unroll
    for (int r = 0; r < 16; ++r) acc[ct][r] = 0.f;

  const int rr = lane >> 4;        // row within 4-row copy group
  const int uu = lane & 15;        // 16B slot within 256B row

  // Wc: swizzled global source + linear LDS dest -> LDS[r][s] = g[s^(r&7)]
  #pragma unroll
  for (int i = 0; i < 8; ++i) {
    int r = w*32 + i*4 + rr;
    async_copy16(&Wc[(size_t)(o0 + r) * CI_ + ((uu ^ (r & 7)) * 8)],
                 &ws_l[(w*32 + i*4) * 128]);
  }
  // y: reg-staged combine; load global slot uu^(r&7), store LDS slot uu
  #pragma unroll
  for (int i = 0; i < 8; ++i) {
    int rl = w*32 + i*4 + rr;
    int n = n0 + rl;
    size_t src = (size_t)n * CI_ + ((uu ^ (rl & 7)) * 8);
    uint4 a0 = *(const uint4*)&yp0[src];
    uint4 a1 = *(const uint4*)&yp1[src];
    float inv = 1.0f / (lp[(size_t)b * N_ + n] + lp[(size_t)(8 + b) * N_ + n]);
    uint4 o;
    o.x = pkbf((bf_lo(a0.x) + bf_lo(a1.x)) * inv, (bf_hi(a0.x) + bf_hi(a1.x)) * inv);
    o.y = pkbf((bf_lo(a0.y) + bf_lo(a1.y)) * inv, (bf_hi(a0.y) + bf_hi(a1.y)) * inv);
    o.z = pkbf((bf_lo(a0.z) + bf_lo(a1.z)) * inv, (bf_hi(a0.z) + bf_hi(a1.z)) * inv);
    o.w = pkbf((bf_lo(a0.w) + bf_lo(a1.w)) * inv, (bf_hi(a0.w) + bf_hi(a1.w)) * inv);
    *(uint4*)&xs_l[rl * 128 + uu * 8] = o;
  }
  __syncthreads();   // drains async copies + LDS writes

  // 32 consecutive MFMAs over K=128
  #pragma unroll
  for (int kk = 0; kk < 8; ++kk) {
    int fc = ((2*kk + h) ^ xk) * 8;
    short8 bf = *(const short8*)&xs_l[(w*32 + l31) * 128 + fc];
    #pragma unroll
    for (int ct = 0; ct < 4; ++ct) {
      short8 af = *(const short8*)&ws_l[(ct*32 + l31) * 128 + fc];
      acc[ct] = __builtin_amdgcn_mfma_f32_32x32x16_bf16(af, bf, acc[ct], 0, 0, 0);
    }
  }

  const int n = n0 + w*32 + l31;
  #pragma unroll
  for (int ct = 0; ct < 4; ++ct)
    #pragma unroll
    for (int rq = 0; rq < 4; ++rq) {
      float4 bv = *(const float4*)&Wb[o0 + ct*32 + 8*rq + 4*h];
      #pragma unroll
      for (int j = 0; j < 4; ++j) {
        int o = o0 + ct*32 + 8*rq + 4*h + j;
        WYb[((size_t)b * C_ + o) * N_ + n] = f2bf(acc[ct][4*rq + j] + (&bv.x)[j]);
      }
    }
}

// -------- BN stats (round-10 proven): 2048 blocks, 2 atomics/block ---------
__global__ __launch_bounds__(256) void bn_stats(
    const ushort_t* __restrict__ WYb, float* __restrict__ st)
{
  const int o  = blockIdx.x & 255;
  const int bb = blockIdx.x >> 8;          // 0..7
  const int tid = threadIdx.x;
  const ushort_t* p = WYb + ((size_t)bb * C_ + o) * N_;
  float s = 0.f, s2 = 0.f;
  #pragma unroll
  for (int j = 0; j < 2; ++j) {
    uint4 v = *(const uint4*)&p[tid * 16 + j * 8];
    float f0 = bf_lo(v.x), f1 = bf_hi(v.x), f2 = bf_lo(v.y), f3 = bf_hi(v.y);
    float f4 = bf_lo(v.z), f5 = bf_hi(v.z), f6 = bf_lo(v.w), f7 = bf_hi(v.w);
    s  += ((f0 + f1) + (f2 + f3)) + ((f4 + f5) + (f6 + f7));
    s2 += ((f0*f0 + f1*f1) + (f2*f2 + f3*f3)) + ((f4*f4 + f5*f5) + (f6*f6 + f7*f7));
  }
  #pragma unroll
  for (int m = 32; m >= 1; m >>= 1) {
    s  += __shfl_xor(s, m);
    s2 += __shfl_xor(s2, m);
  }
  __shared__ float rs[8];
  const int w = tid >> 6, lane = tid & 63;
  if (lane == 0) { rs[w] = s; rs[4 + w] = s2; }
  __syncthreads();
  if (tid == 0) {
    atomicAdd(&st[o],       (rs[0] + rs[1]) + (rs[2] + rs[3]));
    atomicAdd(&st[256 + o], (rs[4] + rs[5]) + (rs[6] + rs[7]));
  }
}

// -------- BN apply (mean/rsqrt from raw sums inline) + residual ------------
__global__ __launch_bounds__(256) void bn_apply(
    const ushort_t* __restrict__ WYb, const float* __restrict__ x,
    const float* __restrict__ st, const float* __restrict__ gamma,
    const float* __restrict__ beta, float* __restrict__ out)
{
  size_t i = ((size_t)blockIdx.x * 256 + threadIdx.x) * 4;
  int o = (int)((i >> 12) & 255);
  uint2 wv = *(const uint2*)&WYb[i];
  float4 xv = *(const float4*)&x[i];
  const float invM = 1.0f / (float)(B_ * N_);
  float mean = st[o] * invM;
  float var  = st[256 + o] * invM - mean * mean;
  float gsc = gamma[o] * rsqrtf(var + 1e-5f);
  float bb  = beta[o] - mean * gsc;
  float4 v;
  v.x = bf_lo(wv.x) * gsc + bb + xv.x;
  v.y = bf_hi(wv.x) * gsc + bb + xv.y;
  v.z = bf_lo(wv.y) * gsc + bb + xv.z;
  v.w = bf_hi(wv.y) * gsc + bb + xv.w;
  *(float4*)&out[i] = v;
}

extern "C" void kernel_launch(void* const* d_in, const int* in_sizes, int n_in,
                              void* d_out, int out_size, void* d_ws, size_t ws_size,
                              hipStream_t stream)
{
  const float* x       = (const float*)d_in[0];
  const float* g_w     = (const float*)d_in[1];
  const float* g_b     = (const float*)d_in[2];
  const float* theta_w = (const float*)d_in[3];
  const float* theta_b = (const float*)d_in[4];
  const float* phi_w   = (const float*)d_in[5];
  const float* phi_b   = (const float*)d_in[6];
  const float* W_w     = (const float*)d_in[7];
  const float* W_b     = (const float*)d_in[8];
  const float* gamma   = (const float*)d_in[9];
  const float* beta    = (const float*)d_in[10];
  float* out = (float*)d_out;

  char* ws = (char*)d_ws;
  ushort_t* W3b = (ushort_t*)(ws + OFF_W3B);
  float*    b3  = (float*)(ws + OFF_B3);
  ushort_t* Wc  = (ushort_t*)(ws + OFF_WCB);
  ushort_t* xt  = (ushort_t*)(ws + OFF_XT);
  ushort_t* tht = (ushort_t*)(ws + OFF_THT);
  ushort_t* pht = (ushort_t*)(ws + OFF_PHT);
  ushort_t* g16 = (ushort_t*)(ws + OFF_G16);
  float*    lpp = (float*)(ws + OFF_LP);
  ushort_t* ypb = (ushort_t*)(ws + OFF_YPB);
  ushort_t* WYb = (ushort_t*)(ws + OFF_WY);   // overlays XT (dead by wgemm)
  float*    ST  = (float*)(ws + OFF_ST);

  pack_xcast<<<2561, 256, 0, stream>>>(g_w, g_b, theta_w, theta_b, phi_w,
                                       phi_b, W_w, x, W3b, b3, Wc, ST, xt);
  proj_all<<<dim3(32, 3, 8), 256, 0, stream>>>(W3b, b3, xt, tht, pht, g16);
  attn_mfma<<<512, 256, 0, stream>>>(tht, pht, g16, ypb, lpp);
  wgemm_fused<<<dim3(32, 2, 8), 256, 0, stream>>>(Wc, W_b, ypb, lpp, WYb);
  bn_stats<<<2048, 256, 0, stream>>>(WYb, ST);
  bn_apply<<<8192, 256, 0, stream>>>(WYb, x, ST, gamma, beta, out);
}

// Round 15
// 225.324 us; speedup vs baseline: 1.4050x; 1.4050x over previous
//
#include <hip/hip_runtime.h>
#include <hip/hip_bf16.h>
#include <math.h>

#define B_   8
#define C_   256
#define CI_  128
#define N_   4096

typedef unsigned short ushort_t;
typedef unsigned int uint_t;
typedef __attribute__((ext_vector_type(8))) short short8;
typedef __attribute__((ext_vector_type(16))) float floatx16;
typedef __attribute__((ext_vector_type(2))) unsigned int uint2v;

// workspace layout (byte offsets)
#define OFF_W3B  0ull           // bf16 [384][256]
#define OFF_B3   196608ull      // fp32 [384]
#define OFF_WCB  198144ull      // bf16 [256][128]
#define OFF_XT   263680ull      // bf16 [B][N][256]      16.8 MB
#define OFF_THT  17040896ull    // bf16 [B][N][128]      8.4 MB
#define OFF_PHT  25429504ull    // bf16 [B][N][128]      8.4 MB
#define OFF_G16  33818112ull    // bf16 [B][128][N]      8.4 MB
#define OFF_LP   42206720ull    // fp32 [2][B][N]        256 KB
#define OFF_YPB  42468864ull    // bf16 [2][B][N][128]   16.8 MB
#define OFF_WY   263680ull      // bf16 [B][256][N] — overlays XT (dead by wgemm)
#define OFF_ST   59246080ull    // fp32 [2][256] raw sums (zeroed by pack path)

__device__ __forceinline__ ushort_t f2bf(float x) {
  union { float f; uint_t u; } c; c.f = x;
  return (ushort_t)((c.u + 0x7fffu + ((c.u >> 16) & 1u)) >> 16);
}
__device__ __forceinline__ uint_t pkbf(float a, float b) {
  __hip_bfloat162 h = __float22bfloat162_rn(float2{a, b});
  union { __hip_bfloat162 h; uint_t u; } c; c.h = h; return c.u;
}
__device__ __forceinline__ float bf_lo(uint_t u) {
  union { uint_t u; float f; } c; c.u = u << 16; return c.f;
}
__device__ __forceinline__ float bf_hi(uint_t u) {
  union { uint_t u; float f; } c; c.u = u & 0xffff0000u; return c.f;
}
// raw hw exp2 (skip OCML denormal-guard path); s_nop covers trans->valu hazard
__device__ __forceinline__ float fexp2(float x) {
  float r; asm("v_exp_f32 %0, %1\ns_nop 0" : "=v"(r) : "v"(x)); return r;
}
__device__ __forceinline__ void async_copy16(const void* g, void* l) {
  __builtin_amdgcn_global_load_lds(
      (const __attribute__((address_space(1))) unsigned int*)g,
      (__attribute__((address_space(3))) unsigned int*)l, 16, 0, 0);
}

// -------- fused: pack weights + zero BN sums + x transpose/cast -------------
// bid < 384: W3b pack; < 512: Wc pack; == 512: zero st; >= 513: xcast tile
__global__ __launch_bounds__(256) void pack_xcast(
    const float* __restrict__ g_w, const float* __restrict__ g_b,
    const float* __restrict__ th_w, const float* __restrict__ th_b,
    const float* __restrict__ ph_w, const float* __restrict__ ph_b,
    const float* __restrict__ W_w, const float* __restrict__ x,
    ushort_t* __restrict__ W3b, float* __restrict__ b3,
    ushort_t* __restrict__ Wc, float* __restrict__ st,
    ushort_t* __restrict__ xt)
{
  const int bid = blockIdx.x;
  const int tid = threadIdx.x;
  __shared__ float xs[64][65];
  if (bid < 384) {
    int i = bid * 256 + tid;
    int o = i >> 8;
    float v;
    if (o < 128)      v = g_w[i];
    else if (o < 256) v = th_w[i - 128*256];
    else              v = ph_w[i - 256*256];
    W3b[i] = f2bf(v);
    if ((i & 255) == 0)
      b3[o] = (o < 128) ? g_b[o] : (o < 256) ? th_b[o - 128] : ph_b[o - 256];
    return;
  } else if (bid < 512) {
    int j = (bid - 384) * 256 + tid;   // < 32768
    Wc[j] = f2bf(W_w[j]);
    return;
  } else if (bid == 512) {
    st[tid] = 0.f;
    st[256 + tid] = 0.f;
    return;
  }
  // xcast: idx -> (b, c-tile, n-tile); 8 x 4 x 64 = 2048 tiles
  const int idx = bid - 513;
  const int b = idx >> 8, cb = (idx >> 6) & 3, nb = idx & 63;
  const int c0 = cb * 64, n0 = nb * 64;
  const int nq = (tid & 15) * 4, cr = tid >> 4;
  #pragma unroll
  for (int i = 0; i < 4; ++i) {
    float4 v = *(const float4*)&x[((size_t)b * C_ + c0 + cr + 16*i) * N_ + n0 + nq];
    xs[cr + 16*i][nq] = v.x; xs[cr + 16*i][nq+1] = v.y;
    xs[cr + 16*i][nq+2] = v.z; xs[cr + 16*i][nq+3] = v.w;
  }
  __syncthreads();
  const int n = tid >> 2, cs = (tid & 3) * 16;
  uint_t u[8];
  #pragma unroll
  for (int j = 0; j < 8; ++j)
    u[j] = pkbf(xs[cs + 2*j][n], xs[cs + 2*j + 1][n]);
  ushort_t* dst = &xt[((size_t)b * N_ + n0 + n) * C_ + c0 + cs];
  *(uint4*)dst       = make_uint4(u[0], u[1], u[2], u[3]);
  *(uint4*)(dst + 8) = make_uint4(u[4], u[5], u[6], u[7]);
}

// -------- projection GEMM v2: double-buffered issue-early staging -----------
__global__ __launch_bounds__(256, 2) void proj_all(
    const ushort_t* __restrict__ W3b, const float* __restrict__ b3,
    const ushort_t* __restrict__ xt, ushort_t* __restrict__ tht,
    ushort_t* __restrict__ pht, ushort_t* __restrict__ g16)
{
  const int b = blockIdx.z, nb = blockIdx.x, ot = blockIdx.y;
  const int gm = (ot == 2);
  const int o0 = gm ? 0 : (128 + ot * 128);
  const int tid = threadIdx.x, w = tid >> 6, lane = tid & 63;
  const int l31 = lane & 31, h = lane >> 5, xk = l31 & 7;
  __shared__ ushort_t ws_l[2 * 128 * 64];   // 32 KB
  __shared__ ushort_t xs_l[2 * 128 * 64];   // 32 KB
  const ushort_t* xb = xt + (size_t)b * N_ * C_;
  const int n0 = nb * 128;
  floatx16 acc[4];
  #pragma unroll
  for (int ct = 0; ct < 4; ++ct)
    #pragma unroll
    for (int r = 0; r < 16; ++r) acc[ct][r] = 0.f;

  const int gr = lane >> 3, gu = lane & 7;

  #define PSTAGE(k0v, bufv)                                                   \
    {                                                                         \
      ushort_t* wsb = ws_l + (bufv) * 8192;                                   \
      ushort_t* xsb = xs_l + (bufv) * 8192;                                   \
      _Pragma("unroll")                                                       \
      for (int i = 0; i < 4; ++i) {                                           \
        int r = w*32 + i*8 + gr;                                              \
        async_copy16(&W3b[(size_t)(o0 + r) * C_ + (k0v) + ((gu ^ (r & 7)) * 8)], \
                     &wsb[(w*32 + i*8) * 64]);                                \
        async_copy16(&xb[(size_t)(n0 + r) * C_ + (k0v) + ((gu ^ (r & 7)) * 8)],  \
                     &xsb[(w*32 + i*8) * 64]);                                \
      }                                                                       \
    }

  PSTAGE(0, 0);
  asm volatile("s_waitcnt vmcnt(0)" ::: "memory");
  __builtin_amdgcn_s_barrier();

  for (int kt = 0; kt < 4; ++kt) {
    const int cur = kt & 1;
    if (kt < 3) PSTAGE((kt + 1) * 64, cur ^ 1);
    const ushort_t* wsb = ws_l + cur * 8192;
    const ushort_t* xsb = xs_l + cur * 8192;
    const ushort_t* bmat = gm ? wsb : xsb;
    const ushort_t* amat = gm ? xsb : wsb;
    #pragma unroll
    for (int kk = 0; kk < 4; ++kk) {
      int fc = ((2*kk + h) ^ xk) * 8;
      short8 bf = *(const short8*)&bmat[(w*32 + l31) * 64 + fc];
      #pragma unroll
      for (int ct = 0; ct < 4; ++ct) {
        short8 af = *(const short8*)&amat[(ct*32 + l31) * 64 + fc];
        acc[ct] = __builtin_amdgcn_mfma_f32_32x32x16_bf16(af, bf, acc[ct], 0, 0, 0);
      }
    }
    asm volatile("s_waitcnt vmcnt(0)" ::: "memory");
    __builtin_amdgcn_s_barrier();
  }

  if (gm) {
    float bv = b3[w*32 + l31];
    ushort_t* gp = g16 + ((size_t)b * CI_ + w*32 + l31) * N_;
    #pragma unroll
    for (int ct = 0; ct < 4; ++ct)
      #pragma unroll
      for (int rq = 0; rq < 4; ++rq) {
        uint2 d = make_uint2(pkbf(acc[ct][4*rq+0] + bv, acc[ct][4*rq+1] + bv),
                             pkbf(acc[ct][4*rq+2] + bv, acc[ct][4*rq+3] + bv));
        *(uint2*)&gp[n0 + ct*32 + 8*rq + 4*h] = d;
      }
  } else {
    ushort_t* tp = ((ot == 0) ? tht : pht) + ((size_t)b * N_ + n0 + w*32 + l31) * CI_;
    #pragma unroll
    for (int ct = 0; ct < 4; ++ct)
      #pragma unroll
      for (int rq = 0; rq < 4; ++rq) {
        float4 bv = *(const float4*)&b3[o0 + ct*32 + 8*rq + 4*h];
        uint2 d = make_uint2(pkbf(acc[ct][4*rq+0] + bv.x, acc[ct][4*rq+1] + bv.y),
                             pkbf(acc[ct][4*rq+2] + bv.z, acc[ct][4*rq+3] + bv.w));
        *(uint2*)&tp[ct*32 + 8*rq + 4*h] = d;
      }
  }
}

// ---------------------------------------------------------------------------
// MFMA flash attention v5 (round-10/13 proven, 91 µs): ms=2, grid 512,
// 48 KB LDS -> 3 blocks/CU, sequential QK halves (no spill at 148/168 regs).
// ---------------------------------------------------------------------------
#define LOG2E_  1.442695041f
#define MBIAS_  (-28.85390082f)   /* = -20 * log2(e) */

__global__ __launch_bounds__(256, 3) void attn_mfma(
    const ushort_t* __restrict__ tht, const ushort_t* __restrict__ pht,
    const ushort_t* __restrict__ g16, ushort_t* __restrict__ yp,
    float* __restrict__ lp)
{
  const int b  = blockIdx.x & 7;           // batch -> XCD
  const int ms = (blockIdx.x >> 3) & 1;    // key split
  const int qb = blockIdx.x >> 4;          // 0..31
  const int tid = threadIdx.x, w = tid >> 6, lane = tid & 63;
  const int l31 = lane & 31, h = lane >> 5, xk = l31 & 7;

  // smem (ushort idx): phs[2] @0 (each 64x128=8192), gs @16384 (128x64=8192)
  __shared__ ushort_t smem[24576];   // 48 KB -> 3 blocks/CU

  const int q0w = qb * 128 + w * 32;
  const int m_base = ms * 2048;

  const ushort_t* thb = tht + (size_t)b * N_ * CI_;
  const ushort_t* phb = pht + (size_t)b * N_ * CI_;
  const ushort_t* gbp = g16 + (size_t)b * CI_ * N_;

  short8 tf[8];
  #pragma unroll
  for (int kk = 0; kk < 8; ++kk)
    tf[kk] = *(const short8*)&thb[(size_t)(q0w + l31) * CI_ + kk*16 + h*8];

  floatx16 acc[4];
  #pragma unroll
  for (int ct = 0; ct < 4; ++ct)
    #pragma unroll
    for (int r = 0; r < 16; ++r) acc[ct][r] = 0.f;
  float lpart = 0.f;

  const int phr = lane >> 4, phu = lane & 15;
  const int gr  = lane >> 3, gu  = lane & 7;

  #define STAGE_PHS(m0v, bufv)                                                \
    {                                                                         \
      ushort_t* phs_ = smem + (bufv) * 8192;                                  \
      _Pragma("unroll")                                                       \
      for (int i = 0; i < 4; ++i) {                                           \
        int row = w*16 + i*4 + phr;                                           \
        async_copy16(&phb[(size_t)((m0v) + row) * CI_ + ((phu ^ (row & 7)) * 8)], \
                     &phs_[(w*16 + i*4) * 128]);                              \
      }                                                                       \
    }
  #define STAGE_GS(m0v)                                                       \
    {                                                                         \
      ushort_t* gs_ = smem + 16384;                                           \
      _Pragma("unroll")                                                       \
      for (int i = 0; i < 4; ++i) {                                           \
        int c = w*32 + i*8 + gr;                                              \
        async_copy16(&gbp[(size_t)c * N_ + (m0v) + ((gu ^ (c & 7)) * 8)],     \
                     &gs_[(w*32 + i*8) * 64]);                                \
      }                                                                       \
    }

  #define SMPV(sv, mtv)                                                       \
    {                                                                         \
      uint_t Aw[4], Bw[4];                                                    \
      float ls = 0.f;                                                         \
      _Pragma("unroll")                                                       \
      for (int rq = 0; rq < 4; ++rq) {                                        \
        float p0 = fexp2(fmaf(sv[4*rq+0], LOG2E_, MBIAS_));                   \
        float p1 = fexp2(fmaf(sv[4*rq+1], LOG2E_, MBIAS_));                   \
        float p2 = fexp2(fmaf(sv[4*rq+2], LOG2E_, MBIAS_));                   \
        float p3 = fexp2(fmaf(sv[4*rq+3], LOG2E_, MBIAS_));                   \
        ls += (p0 + p1) + (p2 + p3);                                          \
        Aw[rq] = pkbf(p0, p1);                                                \
        Bw[rq] = pkbf(p2, p3);                                                \
      }                                                                       \
      lpart += ls;                                                            \
      _Pragma("unroll")                                                       \
      for (int t = 0; t < 2; ++t) {                                           \
        uint2v ra = __builtin_amdgcn_permlane32_swap(Aw[2*t], Aw[2*t+1], false, false); \
        uint2v rb = __builtin_amdgcn_permlane32_swap(Bw[2*t], Bw[2*t+1], false, false); \
        union { uint_t u[4]; short8 s; } pk_;                                 \
        pk_.u[0] = ra.x; pk_.u[1] = rb.x; pk_.u[2] = ra.y; pk_.u[3] = rb.y;   \
        const int pc = ((2*(2*(mtv) + t) + h) ^ xk) * 8;                      \
        __builtin_amdgcn_s_setprio(1);                                        \
        _Pragma("unroll")                                                     \
        for (int ct = 0; ct < 4; ++ct) {                                      \
          short8 gf = *(const short8*)&gs[(ct*32 + l31) * 64 + pc];           \
          acc[ct] = __builtin_amdgcn_mfma_f32_32x32x16_bf16(gf, pk_.s, acc[ct], 0, 0, 0); \
        }                                                                     \
        __builtin_amdgcn_s_setprio(0);                                        \
      }                                                                       \
    }

  const ushort_t* gs = smem + 16384;

  STAGE_PHS(m_base, 0);
  asm volatile("s_waitcnt vmcnt(0)" ::: "memory");
  __builtin_amdgcn_s_barrier();

  for (int it = 0; it < 32; ++it) {
    const int cur = it & 1;
    const int m0 = m_base + it * 64;
    STAGE_GS(m0);
    if (it < 31) STAGE_PHS(m0 + 64, cur ^ 1);
    const ushort_t* phs = smem + cur * 8192;

    // QK^T half 0 (keys m0..m0+31)
    floatx16 s;
    #pragma unroll
    for (int r = 0; r < 16; ++r) s[r] = 0.f;
    __builtin_amdgcn_s_setprio(1);
    #pragma unroll
    for (int kk = 0; kk < 8; ++kk) {
      short8 pf = *(const short8*)&phs[l31 * 128 + (((2*kk + h) ^ xk) * 8)];
      s = __builtin_amdgcn_mfma_f32_32x32x16_bf16(pf, tf[kk], s, 0, 0, 0);
    }
    __builtin_amdgcn_s_setprio(0);

    // own gs copies done (4 newest outstanding = phs(t+1)); barrier -> all
    // waves' gs(t) visible
    if (it < 31) { asm volatile("s_waitcnt vmcnt(4)" ::: "memory"); }
    else         { asm volatile("s_waitcnt vmcnt(0)" ::: "memory"); }
    __builtin_amdgcn_s_barrier();

    SMPV(s, 0)

    // QK^T half 1 (keys m0+32..m0+63); phs[cur] untouched by phs(t+1) writes
    #pragma unroll
    for (int r = 0; r < 16; ++r) s[r] = 0.f;
    __builtin_amdgcn_s_setprio(1);
    #pragma unroll
    for (int kk = 0; kk < 8; ++kk) {
      short8 pf = *(const short8*)&phs[(32 + l31) * 128 + (((2*kk + h) ^ xk) * 8)];
      s = __builtin_amdgcn_mfma_f32_32x32x16_bf16(pf, tf[kk], s, 0, 0, 0);
    }
    __builtin_amdgcn_s_setprio(0);

    SMPV(s, 1)

    // phs(t+1) (issued a full iter ago) drained; barrier separates this
    // iter's phs/gs reads from next iter's DMA writes
    asm volatile("s_waitcnt vmcnt(0)" ::: "memory");
    __builtin_amdgcn_s_barrier();
  }

  float lq = lpart + __shfl_xor(lpart, 32);
  if (h == 0)
    lp[((size_t)ms * 8 + b) * N_ + q0w + l31] = lq;

  __syncthreads();
  ushort_t* tr = smem + w * 4096;
  #pragma unroll
  for (int ct = 0; ct < 4; ++ct)
    #pragma unroll
    for (int rq = 0; rq < 4; ++rq) {
      uint2 d = make_uint2(pkbf(acc[ct][4*rq+0], acc[ct][4*rq+1]),
                           pkbf(acc[ct][4*rq+2], acc[ct][4*rq+3]));
      *(uint2*)&tr[l31 * 128 + ct*32 + 8*rq + 4*h] = d;
    }
  ushort_t* ypb = yp + (((size_t)ms * 8 + b) * N_ + q0w) * CI_;
  #pragma unroll
  for (int itx = 0; itx < 8; ++itx) {
    int row = itx*4 + (lane >> 4);
    int cu  = (lane & 15) * 8;
    uint4 v = *(const uint4*)&tr[row * 128 + cu];
    *(uint4*)&ypb[(size_t)row * CI_ + cu] = v;
  }
}

// -------- W-conv GEMM v2 (round-10 proven): single-shot K=128, one barrier --
__global__ __launch_bounds__(256, 2) void wgemm_fused(
    const ushort_t* __restrict__ Wc, const float* __restrict__ Wb,
    const ushort_t* __restrict__ yp, const float* __restrict__ lp,
    ushort_t* __restrict__ WYb)
{
  const int b = blockIdx.z, nb = blockIdx.x, ot = blockIdx.y;
  const int o0 = ot * 128;
  const int tid = threadIdx.x, w = tid >> 6, lane = tid & 63;
  const int l31 = lane & 31, h = lane >> 5, xk = l31 & 7;
  __shared__ ushort_t ws_l[128 * 128];   // 32 KB: Wc [o_local][c]
  __shared__ ushort_t xs_l[128 * 128];   // 32 KB: y  [n_local][c]
  const int n0 = nb * 128;
  const size_t PH = (size_t)B_ * N_ * CI_;
  const ushort_t* yp0 = yp + (size_t)b * N_ * CI_;
  const ushort_t* yp1 = yp0 + PH;
  floatx16 acc[4];
  #pragma unroll
  for (int ct = 0; ct < 4; ++ct)
    #pragma unroll
    for (int r = 0; r < 16; ++r) acc[ct][r] = 0.f;

  const int rr = lane >> 4;        // row within 4-row copy group
  const int uu = lane & 15;        // 16B slot within 256B row

  // Wc: swizzled global source + linear LDS dest -> LDS[r][s] = g[s^(r&7)]
  #pragma unroll
  for (int i = 0; i < 8; ++i) {
    int r = w*32 + i*4 + rr;
    async_copy16(&Wc[(size_t)(o0 + r) * CI_ + ((uu ^ (r & 7)) * 8)],
                 &ws_l[(w*32 + i*4) * 128]);
  }
  // y: reg-staged combine; load global slot uu^(r&7), store LDS slot uu
  #pragma unroll
  for (int i = 0; i < 8; ++i) {
    int rl = w*32 + i*4 + rr;
    int n = n0 + rl;
    size_t src = (size_t)n * CI_ + ((uu ^ (rl & 7)) * 8);
    uint4 a0 = *(const uint4*)&yp0[src];
    uint4 a1 = *(const uint4*)&yp1[src];
    float inv = 1.0f / (lp[(size_t)b * N_ + n] + lp[(size_t)(8 + b) * N_ + n]);
    uint4 o;
    o.x = pkbf((bf_lo(a0.x) + bf_lo(a1.x)) * inv, (bf_hi(a0.x) + bf_hi(a1.x)) * inv);
    o.y = pkbf((bf_lo(a0.y) + bf_lo(a1.y)) * inv, (bf_hi(a0.y) + bf_hi(a1.y)) * inv);
    o.z = pkbf((bf_lo(a0.z) + bf_lo(a1.z)) * inv, (bf_hi(a0.z) + bf_hi(a1.z)) * inv);
    o.w = pkbf((bf_lo(a0.w) + bf_lo(a1.w)) * inv, (bf_hi(a0.w) + bf_hi(a1.w)) * inv);
    *(uint4*)&xs_l[rl * 128 + uu * 8] = o;
  }
  __syncthreads();   // drains async copies + LDS writes

  // 32 consecutive MFMAs over K=128
  #pragma unroll
  for (int kk = 0; kk < 8; ++kk) {
    int fc = ((2*kk + h) ^ xk) * 8;
    short8 bf = *(const short8*)&xs_l[(w*32 + l31) * 128 + fc];
    #pragma unroll
    for (int ct = 0; ct < 4; ++ct) {
      short8 af = *(const short8*)&ws_l[(ct*32 + l31) * 128 + fc];
      acc[ct] = __builtin_amdgcn_mfma_f32_32x32x16_bf16(af, bf, acc[ct], 0, 0, 0);
    }
  }

  const int n = n0 + w*32 + l31;
  #pragma unroll
  for (int ct = 0; ct < 4; ++ct)
    #pragma unroll
    for (int rq = 0; rq < 4; ++rq) {
      float4 bv = *(const float4*)&Wb[o0 + ct*32 + 8*rq + 4*h];
      #pragma unroll
      for (int j = 0; j < 4; ++j) {
        int o = o0 + ct*32 + 8*rq + 4*h + j;
        WYb[((size_t)b * C_ + o) * N_ + n] = f2bf(acc[ct][4*rq + j] + (&bv.x)[j]);
      }
    }
}

// -------- BN stats (round-10 proven): 2048 blocks, 2 atomics/block ---------
__global__ __launch_bounds__(256) void bn_stats(
    const ushort_t* __restrict__ WYb, float* __restrict__ st)
{
  const int o  = blockIdx.x & 255;
  const int bb = blockIdx.x >> 8;          // 0..7
  const int tid = threadIdx.x;
  const ushort_t* p = WYb + ((size_t)bb * C_ + o) * N_;
  float s = 0.f, s2 = 0.f;
  #pragma unroll
  for (int j = 0; j < 2; ++j) {
    uint4 v = *(const uint4*)&p[tid * 16 + j * 8];
    float f0 = bf_lo(v.x), f1 = bf_hi(v.x), f2 = bf_lo(v.y), f3 = bf_hi(v.y);
    float f4 = bf_lo(v.z), f5 = bf_hi(v.z), f6 = bf_lo(v.w), f7 = bf_hi(v.w);
    s  += ((f0 + f1) + (f2 + f3)) + ((f4 + f5) + (f6 + f7));
    s2 += ((f0*f0 + f1*f1) + (f2*f2 + f3*f3)) + ((f4*f4 + f5*f5) + (f6*f6 + f7*f7));
  }
  #pragma unroll
  for (int m = 32; m >= 1; m >>= 1) {
    s  += __shfl_xor(s, m);
    s2 += __shfl_xor(s2, m);
  }
  __shared__ float rs[8];
  const int w = tid >> 6, lane = tid & 63;
  if (lane == 0) { rs[w] = s; rs[4 + w] = s2; }
  __syncthreads();
  if (tid == 0) {
    atomicAdd(&st[o],       (rs[0] + rs[1]) + (rs[2] + rs[3]));
    atomicAdd(&st[256 + o], (rs[4] + rs[5]) + (rs[6] + rs[7]));
  }
}

// -------- BN apply (mean/rsqrt from raw sums inline) + residual ------------
__global__ __launch_bounds__(256) void bn_apply(
    const ushort_t* __restrict__ WYb, const float* __restrict__ x,
    const float* __restrict__ st, const float* __restrict__ gamma,
    const float* __restrict__ beta, float* __restrict__ out)
{
  size_t i = ((size_t)blockIdx.x * 256 + threadIdx.x) * 4;
  int o = (int)((i >> 12) & 255);
  uint2 wv = *(const uint2*)&WYb[i];
  float4 xv = *(const float4*)&x[i];
  const float invM = 1.0f / (float)(B_ * N_);
  float mean = st[o] * invM;
  float var  = st[256 + o] * invM - mean * mean;
  float gsc = gamma[o] * rsqrtf(var + 1e-5f);
  float bb  = beta[o] - mean * gsc;
  float4 v;
  v.x = bf_lo(wv.x) * gsc + bb + xv.x;
  v.y = bf_hi(wv.x) * gsc + bb + xv.y;
  v.z = bf_lo(wv.y) * gsc + bb + xv.z;
  v.w = bf_hi(wv.y) * gsc + bb + xv.w;
  *(float4*)&out[i] = v;
}

extern "C" void kernel_launch(void* const* d_in, const int* in_sizes, int n_in,
                              void* d_out, int out_size, void* d_ws, size_t ws_size,
                              hipStream_t stream)
{
  const float* x       = (const float*)d_in[0];
  const float* g_w     = (const float*)d_in[1];
  const float* g_b     = (const float*)d_in[2];
  const float* theta_w = (const float*)d_in[3];
  const float* theta_b = (const float*)d_in[4];
  const float* phi_w   = (const float*)d_in[5];
  const float* phi_b   = (const float*)d_in[6];
  const float* W_w     = (const float*)d_in[7];
  const float* W_b     = (const float*)d_in[8];
  const float* gamma   = (const float*)d_in[9];
  const float* beta    = (const float*)d_in[10];
  float* out = (float*)d_out;

  char* ws = (char*)d_ws;
  ushort_t* W3b = (ushort_t*)(ws + OFF_W3B);
  float*    b3  = (float*)(ws + OFF_B3);
  ushort_t* Wc  = (ushort_t*)(ws + OFF_WCB);
  ushort_t* xt  = (ushort_t*)(ws + OFF_XT);
  ushort_t* tht = (ushort_t*)(ws + OFF_THT);
  ushort_t* pht = (ushort_t*)(ws + OFF_PHT);
  ushort_t* g16 = (ushort_t*)(ws + OFF_G16);
  float*    lpp = (float*)(ws + OFF_LP);
  ushort_t* ypb = (ushort_t*)(ws + OFF_YPB);
  ushort_t* WYb = (ushort_t*)(ws + OFF_WY);   // overlays XT (dead by wgemm)
  float*    ST  = (float*)(ws + OFF_ST);

  pack_xcast<<<2561, 256, 0, stream>>>(g_w, g_b, theta_w, theta_b, phi_w,
                                       phi_b, W_w, x, W3b, b3, Wc, ST, xt);
  proj_all<<<dim3(32, 3, 8), 256, 0, stream>>>(W3b, b3, xt, tht, pht, g16);
  attn_mfma<<<512, 256, 0, stream>>>(tht, pht, g16, ypb, lpp);
  wgemm_fused<<<dim3(32, 2, 8), 256, 0, stream>>>(Wc, W_b, ypb, lpp, WYb);
  bn_stats<<<2048, 256, 0, stream>>>(WYb, ST);
  bn_apply<<<8192, 256, 0, stream>>>(WYb, x, ST, gamma, beta, out);
}